// Round 4
// baseline (493.887 us; speedup 1.0000x reference)
//
#include <hip/hip_runtime.h>
#include <stdint.h>

#define K_DIM 4096
#define N_DIM 4096
#define M_DIM 8192

// GEMM tile geometry: 256x256 tile, BK=64, 8-phase dbuf half-tile pipeline
#define BM 256
#define BN 256
#define BK 64
#define NT (K_DIM / BK)          // 64 K-tiles = 32 iterations of 2

typedef __bf16 bf16x8 __attribute__((ext_vector_type(8)));
typedef _Float16 f16x8 __attribute__((ext_vector_type(8)));
typedef unsigned short u16x8 __attribute__((ext_vector_type(8)));
typedef float floatx4 __attribute__((ext_vector_type(4)));

// Device-global scratch (module .bss). Stored dtype-neutral as u16:
//   g_Bt: fp16 when x is fp16/f32 (f16-MFMA path), bf16 when x is bf16.
//   g_X : fp16 conversion of x, only used when x is f32 (mode 1).
__device__ __attribute__((aligned(256))) unsigned short g_Bt[(size_t)N_DIM * K_DIM];
__device__ __attribute__((aligned(256))) unsigned short g_X [(size_t)M_DIM * K_DIM];
__device__ int g_flags[2];  // [0]: x dtype 0=bf16 1=f32 2=fp16 ; [1]: perm is candB
__device__ int g_counts[4]; // probe partials; re-zeroed by finalize each call

__device__ __forceinline__ void global_to_lds16(const void* g, void* l) {
    // width=16 async global->LDS; LDS dest = wave-uniform base + lane*16 (linear!)
    __builtin_amdgcn_global_load_lds(
        (const __attribute__((address_space(1))) uint32_t*)g,
        (__attribute__((address_space(3))) uint32_t*)l,
        16, 0, 0);
}

#define LDS_FENCE() asm volatile("" ::: "memory")
#define BARRIER() do { LDS_FENCE(); __builtin_amdgcn_s_barrier(); LDS_FENCE(); } while (0)

// ---------------- probe (32 blocks, parallel) + finalize ----------------
__global__ void probe_kernel(const void* xraw, const int* candA, const int* candB) {
    __shared__ int s[4];
    if (threadIdx.x < 4) s[threadIdx.x] = 0;
    __syncthreads();
    const uint16_t* xw = (const uint16_t*)xraw;
    const int gidx = blockIdx.x * 256 + threadIdx.x;   // 8192 samples total
    int insane = 0, small = 0;
    {
        uint16_t a = (uint16_t)(xw[2 * gidx] & 0x7FFF); // EVEN 16-bit words of x
        if (a >= 0x4300) insane++;                      // f32 mantissa junk ~48%; bf16 ~0
        if (a > 0 && a < 0x3000) small++;               // fp16 N(0,1) ~10%; bf16 ~0
    }
    int badA = 0, badB = 0;
    if (gidx < 4096) {
        if ((unsigned)candA[gidx] >= 4096u) badA++;     // permutation: all in [0,4096)
        if ((unsigned)candB[gidx] >= 4096u) badB++;
    }
    atomicAdd(&s[0], insane); atomicAdd(&s[1], small);
    atomicAdd(&s[2], badA);   atomicAdd(&s[3], badB);
    __syncthreads();
    if (threadIdx.x < 4 && s[threadIdx.x] != 0) atomicAdd(&g_counts[threadIdx.x], s[threadIdx.x]);
}

__global__ void finalize_kernel() {
    int insane = g_counts[0], small = g_counts[1];
    int badA = g_counts[2], badB = g_counts[3];
    int mode = 0;
    if (insane > 32) mode = 1;            // float32
    else if (small > 100) mode = 2;       // float16
    g_flags[0] = mode;
    g_flags[1] = (badA > 0 && badB == 0) ? 1 : 0;
    g_counts[0] = g_counts[1] = g_counts[2] = g_counts[3] = 0;  // reset for next call
}

// ---------------- normalize x -> fp16 g_X (ONLY when x is f32) ----------------
__global__ void __launch_bounds__(256) convert_x_kernel(const void* xraw) {
    if (g_flags[0] != 1) return;
    const size_t nchunk = (size_t)M_DIM * K_DIM / 8;
    const float* xf = (const float*)xraw;
    for (size_t c = (size_t)blockIdx.x * 256 + threadIdx.x; c < nchunk;
         c += (size_t)gridDim.x * 256) {
        size_t base = c * 8;
        float4 v0 = *(const float4*)(xf + base);
        float4 v1 = *(const float4*)(xf + base + 4);
        u16x8 o;
        _Float16 h;
        h = (_Float16)v0.x; o[0] = __builtin_bit_cast(unsigned short, h);
        h = (_Float16)v0.y; o[1] = __builtin_bit_cast(unsigned short, h);
        h = (_Float16)v0.z; o[2] = __builtin_bit_cast(unsigned short, h);
        h = (_Float16)v0.w; o[3] = __builtin_bit_cast(unsigned short, h);
        h = (_Float16)v1.x; o[4] = __builtin_bit_cast(unsigned short, h);
        h = (_Float16)v1.y; o[5] = __builtin_bit_cast(unsigned short, h);
        h = (_Float16)v1.z; o[6] = __builtin_bit_cast(unsigned short, h);
        h = (_Float16)v1.w; o[7] = __builtin_bit_cast(unsigned short, h);
        *(u16x8*)(g_X + base) = o;
    }
}

// ---------------- dequant + K-perm folded into weights (r2 LDS-transpose version) ----------------
__global__ void __launch_bounds__(256) dequant_perm_kernel(
    const int* __restrict__ q_weight,        // [K/8][N]
    const int* __restrict__ q_scale,         // [G][N/8]
    const void* __restrict__ qsm_raw,        // [G] (dtype per flag)
    const int* __restrict__ candA, const int* __restrict__ candB)
{
    __shared__ __attribute__((aligned(16))) unsigned short lds[16 * 136];

    const int mode = g_flags[0];
    const int* q_invperm = g_flags[1] ? candB : candA;

    const int n_l  = threadIdx.x & 15;
    const int jp_l = threadIdx.x >> 4;
    const int n  = blockIdx.x * 16 + n_l;              // 16 contiguous n per group
    const int j0 = (blockIdx.y * 16 + jp_l) << 3;      // j-pack (8 outputs)

    int4 ip0 = *(const int4*)(q_invperm + j0);
    int4 ip1 = *(const int4*)(q_invperm + j0 + 4);
    int ks[8] = {ip0.x, ip0.y, ip0.z, ip0.w, ip1.x, ip1.y, ip1.z, ip1.w};

    const int nshift = (n & 7) << 2;
    const int scol = n >> 3;

    u16x8 ov;
#pragma unroll
    for (int u = 0; u < 8; ++u) {
        int k = ks[u] & (K_DIM - 1);
        int w4 = (q_weight[(size_t)(k >> 3) * N_DIM + n] >> ((k & 7) << 2)) & 0xF;
        int g = k >> 7;
        int s4 = (q_scale[g * (N_DIM / 8) + scol] >> nshift) & 0xF;
        float smax;
        if (mode == 1)      smax = ((const float*)qsm_raw)[g];
        else if (mode == 2) smax = (float)((const _Float16*)qsm_raw)[g];
        else                smax = (float)((const __bf16*)qsm_raw)[g];
        float sp1 = (float)(s4 + 1);
        float w = (float)(w4 - 8) * (sp1 * sp1 * smax * (1.0f / 256.0f));
        if (mode != 0) { _Float16 h = (_Float16)w; ov[u] = __builtin_bit_cast(unsigned short, h); }
        else           { __bf16   b = (__bf16)w;   ov[u] = __builtin_bit_cast(unsigned short, b); }
    }
    *(u16x8*)&lds[n_l * 136 + jp_l * 8] = ov;
    __syncthreads();

    const int row = threadIdx.x >> 4;
    const int c16 = threadIdx.x & 15;
    u16x8 t = *(const u16x8*)&lds[row * 136 + c16 * 8];
    *(u16x8*)(g_Bt + (size_t)(blockIdx.x * 16 + row) * K_DIM
              + (size_t)blockIdx.y * 128 + c16 * 8) = t;
}

// ---------------- GEMM: C = X * g_Bt^T + bias ----------------
// m201-style 8-phase schedule. 256x256 tile, BK=64, 8 waves with INTERLEAVED
// stripes: wave wm (0-1) owns m rows mh*128 + wm*64 + fi*16; wave wn (0-3)
// owns n rows nh*128 + wn*32 + fj*16. Phase quad(mh,nh) therefore reads
// exactly A-half mh + B-half nh block-wide -> halves free progressively.
// 2 barriers/phase: stage into a half freed at phase p can only land after
// every wave's lgkmcnt(0)+MFMA of phase p (between the barriers) -> provably
// race-free. Stage map (into freed halves, 2 gloads per half-tile):
//   ph0: Q.B1(cur Q tile) | ph1: P.A0(t+2) | ph3: P.A1(t+2)
//   ph4: P.B0+P.B1(t+2)   | ph5: Q.A0(t+3) | ph7: Q.A1+Q.B0(t+3)
// vmcnt ledger: vmcnt(4) at ph3-end, vmcnt(6) at ph7-end (publish barriers).
// Never 0 in steady state. XOR-swizzle wiring identical to r1-r3 (0 conflicts).
template <bool F16>
__global__ void __launch_bounds__(512, 2) gemm_bt_kernel(
    const void* __restrict__ xraw,
    const void* __restrict__ bias_candA, const void* __restrict__ bias_candB,
    void* __restrict__ outraw)
{
    const int mode = g_flags[0];
    if (F16 != (mode != 0)) return;            // wrong instantiation: exit (~us)

    // A: [2 dbuf][2 half][128 rows][64 k] = 64 KiB ; B same = 64 KiB; total 128 KiB
    __shared__ __attribute__((aligned(128))) unsigned short sm[65536];

    const void* bias_raw = g_flags[1] ? bias_candA : bias_candB; // perm==B -> bias==A
    const unsigned short* __restrict__ Xp =
        (mode == 1) ? g_X : (const unsigned short*)xraw;
    const unsigned short* __restrict__ Bt = g_Bt;

    const int tid  = threadIdx.x;
    const int wave = tid >> 6;
    const int lane = tid & 63;

    // grid 16 x 32 = 512 wgs; bijective XCD swizzle (512 % 8 == 0)
    const int orig = blockIdx.y * 16 + blockIdx.x;
    const int swz  = (orig & 7) * 64 + (orig >> 3);
    const int bn0  = (swz & 15) * BN;
    const int bm0  = (swz >> 4) * BM;

    // ---- staging geometry: per gload one wave covers 8 rows x 64 k = 1 KiB ----
    const int lrow8 = lane >> 3;                        // row within 8-row chunk
    const int ksw   = ((lane & 7) ^ lrow8) << 3;        // inverse-swizzled global k (elems)
    const unsigned short* Xs = Xp + (size_t)(bm0 + wave * 8 + lrow8) * K_DIM + ksw;
    const unsigned short* Bs = Bt + (size_t)(bn0 + wave * 8 + lrow8) * K_DIM + ksw;
    const int sdst = wave * 512 + lane * 8;             // LDS elem offset within chunk

    // ---- fragment geometry (interleaved stripes) ----
    const int wm   = wave >> 2;                         // 0..1
    const int wn   = wave & 3;                          // 0..3
    const int frow = lane & 15;
    const int fk   = (lane >> 4) << 3;                  // 0,8,16,24
    const int kx   = (lane & 7) << 3;                   // read-side swizzle XOR (elems)
    const int arow = (wm * 64 + frow) * 64;             // + fi*1024 + mh*8192
    const int brow = (wn * 32 + frow) * 64;             // + fj*1024 + nh*8192

    floatx4 acc[2][2][4][2] = {};                       // [mh][nh][fi][fj]
    u16x8 a[4][2];                                      // [fi][k2], current mh
    u16x8 b[2][2][2];                                   // [nh][fj][k2], current K-tile

#define VM4() asm volatile("s_waitcnt vmcnt(4)" ::: "memory")
#define VM6() asm volatile("s_waitcnt vmcnt(6)" ::: "memory")
#define VM0() asm volatile("s_waitcnt vmcnt(0)" ::: "memory")
#define LG0() asm volatile("s_waitcnt lgkmcnt(0)" ::: "memory")

#define ST_A(d, h, kt) do { \
    _Pragma("unroll") for (int r = 0; r < 2; ++r) \
        global_to_lds16(Xs + (size_t)((h) * 128 + r * 64) * K_DIM + (kt), \
                        &sm[(d) * 16384 + (h) * 8192 + r * 4096 + sdst]); } while (0)
#define ST_B(d, h, kt) do { \
    _Pragma("unroll") for (int r = 0; r < 2; ++r) \
        global_to_lds16(Bs + (size_t)((h) * 128 + r * 64) * K_DIM + (kt), \
                        &sm[32768 + (d) * 16384 + (h) * 8192 + r * 4096 + sdst]); } while (0)
#define RD_A(d, mh) do { \
    _Pragma("unroll") for (int fi = 0; fi < 4; ++fi) \
    _Pragma("unroll") for (int k2 = 0; k2 < 2; ++k2) \
        a[fi][k2] = *(const u16x8*)&sm[(d) * 16384 + (mh) * 8192 + arow + fi * 1024 \
                                       + ((k2 * 32 + fk) ^ kx)]; } while (0)
#define RD_B(d, nh) do { \
    _Pragma("unroll") for (int fj = 0; fj < 2; ++fj) \
    _Pragma("unroll") for (int k2 = 0; k2 < 2; ++k2) \
        b[nh][fj][k2] = *(const u16x8*)&sm[32768 + (d) * 16384 + (nh) * 8192 + brow + fj * 1024 \
                                           + ((k2 * 32 + fk) ^ kx)]; } while (0)
#define MM16(mh, nh) do { \
    __builtin_amdgcn_s_setprio(1); \
    _Pragma("unroll") for (int fi = 0; fi < 4; ++fi) \
    _Pragma("unroll") for (int fj = 0; fj < 2; ++fj) \
    _Pragma("unroll") for (int k2 = 0; k2 < 2; ++k2) { \
        if constexpr (F16) \
            acc[mh][nh][fi][fj] = __builtin_amdgcn_mfma_f32_16x16x32_f16( \
                __builtin_bit_cast(f16x8, a[fi][k2]), __builtin_bit_cast(f16x8, b[nh][fj][k2]), \
                acc[mh][nh][fi][fj], 0, 0, 0); \
        else \
            acc[mh][nh][fi][fj] = __builtin_amdgcn_mfma_f32_16x16x32_bf16( \
                __builtin_bit_cast(bf16x8, a[fi][k2]), __builtin_bit_cast(bf16x8, b[nh][fj][k2]), \
                acc[mh][nh][fi][fj], 0, 0, 0); \
    } \
    __builtin_amdgcn_s_setprio(0); } while (0)

    // ---- prologue: P(t0) fully (8 loads), Q(t1) minus B1 (6 loads) ----
    ST_A(0, 0, 0); ST_A(0, 1, 0); ST_B(0, 0, 0); ST_B(0, 1, 0);
    ST_A(1, 0, BK); ST_A(1, 1, BK); ST_B(1, 0, BK);
    VM6();                                   // P(t0) resident; Q partials in flight
    BARRIER();

#pragma unroll 1
    for (int J = 0; J < NT / 2; ++J) {
        const int kQ  = 2 * J * BK + BK;     // current Q tile k-offset
        const int kP2 = 2 * J * BK + 2 * BK; // prefetch P (t+2)
        const int kQ2 = 2 * J * BK + 3 * BK; // prefetch Q (t+3)
        const bool stg = (J + 1 < NT / 2);

        // ======== K-tile P (dbuf 0) ========
        // ph0: quad(0,0) — reads A.h0 + B.h0; stage current Q.B1
        RD_A(0, 0); RD_B(0, 0);
        ST_B(1, 1, kQ);
        BARRIER(); LG0(); MM16(0, 0); BARRIER();

        // ph1: quad(0,1) — reads B.h1 (A reused); stage P.A0(t+2)
        RD_B(0, 1);
        if (stg) ST_A(0, 0, kP2);
        BARRIER(); LG0(); MM16(0, 1); BARRIER();

        // ph2: quad(1,0) — reads A.h1 (B reused)
        RD_A(0, 1);
        BARRIER(); LG0(); MM16(1, 0); BARRIER();

        // ph3: quad(1,1) — no reads; stage P.A1(t+2); publish-wait for Q tile
        if (stg) ST_A(0, 1, kP2);
        BARRIER(); LG0(); MM16(1, 1);
        if (stg) VM4(); else VM0();          // Q(t+1) fully landed (incl. ph0's B1)
        BARRIER();

        // ======== K-tile Q (dbuf 1) ========
        // ph4: quad(0,0); stage P.B0+B1(t+2)
        RD_A(1, 0); RD_B(1, 0);
        if (stg) { ST_B(0, 0, kP2); ST_B(0, 1, kP2); }
        BARRIER(); LG0(); MM16(0, 0); BARRIER();

        // ph5: quad(0,1); stage Q.A0(t+3)
        RD_B(1, 1);
        if (stg) ST_A(1, 0, kQ2);
        BARRIER(); LG0(); MM16(0, 1); BARRIER();

        // ph6: quad(1,0)
        RD_A(1, 1);
        BARRIER(); LG0(); MM16(1, 0); BARRIER();

        // ph7: quad(1,1); stage Q.A1+Q.B0(t+3); publish-wait for next P tile
        if (stg) { ST_A(1, 1, kQ2); ST_B(1, 0, kQ2); }
        BARRIER(); LG0(); MM16(1, 1);
        if (stg) VM6();                      // P(t+2) fully landed for next ph0
        BARRIER();
    }

    // Epilogue: C/D layout col=lane&15, row=(lane>>4)*4+reg  [m89-verified]
    const int ccol = lane & 15;
    const int crow = (lane >> 4) << 2;
#pragma unroll
    for (int mh = 0; mh < 2; ++mh)
#pragma unroll
    for (int nh = 0; nh < 2; ++nh)
#pragma unroll
    for (int fj = 0; fj < 2; ++fj) {
        const int col = bn0 + nh * 128 + wn * 32 + fj * 16 + ccol;
        float bv;
        if (mode == 1)      bv = ((const float*)bias_raw)[col];
        else if (mode == 2) bv = (float)((const _Float16*)bias_raw)[col];
        else                bv = (float)((const __bf16*)bias_raw)[col];
#pragma unroll
        for (int fi = 0; fi < 4; ++fi) {
            const int row = bm0 + mh * 128 + wm * 64 + fi * 16 + crow;
#pragma unroll
            for (int r = 0; r < 4; ++r) {
                float v = acc[mh][nh][fi][fj][r] + bv;
                size_t idx = (size_t)(row + r) * N_DIM + col;
                if (mode == 1)      ((float*)outraw)[idx] = v;
                else if (mode == 2) ((_Float16*)outraw)[idx] = (_Float16)v;
                else                ((__bf16*)outraw)[idx] = (__bf16)v;
            }
        }
    }
#undef ST_A
#undef ST_B
#undef RD_A
#undef RD_B
#undef MM16
#undef VM4
#undef VM6
#undef VM0
#undef LG0
}

extern "C" void kernel_launch(void* const* d_in, const int* in_sizes, int n_in,
                              void* d_out, int out_size, void* d_ws, size_t ws_size,
                              hipStream_t stream) {
    // Map inputs by element count (d_in is NOT in dict order).
    int idx_x = 0, idx_qw = 1, idx_qs = 2, idx_qsm = 3, idx_a = -1, idx_b = -1;
    for (int i = 0; i < n_in; ++i) {
        switch (in_sizes[i]) {
            case 33554432: idx_x = i; break;                       // x [8192][4096]
            case 2097152:  idx_qw = i; break;                      // q_weight [512][4096]
            case 16384:    idx_qs = i; break;                      // q_scale [32][512]
            case 32:       idx_qsm = i; break;                     // q_scale_max [32]
            case 4096:     (idx_a < 0 ? idx_a : idx_b) = i; break; // q_invperm / bias
            default: break;
        }
    }
    if (idx_a < 0) idx_a = 4;
    if (idx_b < 0) idx_b = 5;

    const void* xraw  = d_in[idx_x];
    const int*  qw    = (const int*)d_in[idx_qw];
    const int*  qs    = (const int*)d_in[idx_qs];
    const void* qsm   = d_in[idx_qsm];
    const int*  candA = (const int*)d_in[idx_a];
    const int*  candB = (const int*)d_in[idx_b];

    probe_kernel<<<32, 256, 0, stream>>>(xraw, candA, candB);
    finalize_kernel<<<1, 1, 0, stream>>>();
    convert_x_kernel<<<2048, 256, 0, stream>>>(xraw);   // f32 inputs only; exits otherwise
    dim3 dqg(N_DIM / 16, (K_DIM / 8) / 16);             // 16 n x 128 j tile per block
    dequant_perm_kernel<<<dqg, 256, 0, stream>>>(qw, qs, qsm, candA, candB);
    dim3 grid(N_DIM / BN, M_DIM / BM);                  // (16, 32)
    gemm_bt_kernel<true ><<<grid, 512, 0, stream>>>(xraw, d_in[idx_a], d_in[idx_b], d_out);
    gemm_bt_kernel<false><<<grid, 512, 0, stream>>>(xraw, d_in[idx_a], d_in[idx_b], d_out);
}